// Round 8
// baseline (2827.419 us; speedup 1.0000x reference)
//
#include <hip/hip_runtime.h>

#define E 64
#define D 50
#define SS 384
#define G4 256   // 4*E

__device__ __forceinline__ float fast_rcp(float x){ return __builtin_amdgcn_rcpf(x); }
__device__ __forceinline__ float tanh_fast(float x){
  // tanh(x) = 1 - 2/(exp(2x)+1)
  float e = __expf(2.0f*x);
  return 1.0f - 2.0f*fast_rcp(e + 1.0f);
}
__device__ __forceinline__ float sigmoid_fast(float x){
  return fast_rcp(1.0f + __expf(-x));
}
__device__ __forceinline__ float rdlane(float v, int l){
  return __int_as_float(__builtin_amdgcn_readlane(__float_as_int(v), l));
}
// DPP-shifted copy with 0 for invalid source lanes (ctrl must be a literal).
#define DPP0(x, ctrl) __int_as_float(__builtin_amdgcn_update_dpp( \
    0, __float_as_int(x), ctrl, 0xF, 0xF, true))
// wave64 sum; full sum valid in lane 63 (classic row_shr + row_bcast ladder)
__device__ __forceinline__ float wave_sum64_l63(float x){
  x += DPP0(x, 0x111);  // row_shr:1
  x += DPP0(x, 0x112);  // row_shr:2
  x += DPP0(x, 0x114);  // row_shr:4
  x += DPP0(x, 0x118);  // row_shr:8
  x += DPP0(x, 0x142);  // row_bcast:15
  x += DPP0(x, 0x143);  // row_bcast:31
  return x;
}
// Block barrier that drains ONLY the LDS counter (no vmcnt(0) drain).
__device__ __forceinline__ void barrier_lds_only(){
  __builtin_amdgcn_sched_barrier(0);
  asm volatile("s_waitcnt lgkmcnt(0)" ::: "memory");
  __builtin_amdgcn_s_barrier();
  __builtin_amdgcn_sched_barrier(0);
}

// ---------------------------------------------------------------------------
// K0: gx[b,s,j] = bias[j] + sum_k emb[sent[b,s],k] * Wih[j,k]   (both LSTMs)
// ---------------------------------------------------------------------------
__global__ __launch_bounds__(256, 1) void gx_kernel(
  const int* __restrict__ sent1, const int* __restrict__ sent2,
  const float* __restrict__ emb,
  const float* __restrict__ Wih1, const float* __restrict__ bih1, const float* __restrict__ bhh1,
  const float* __restrict__ Wih2, const float* __restrict__ bih2, const float* __restrict__ bhh2,
  float* __restrict__ gx1, float* __restrict__ gx2)
{
  const int bb    = blockIdx.x;     // 0..511
  const int which = bb >> 8;
  const int chunk = bb & 255;
  const int j     = threadIdx.x;
  const int*   sent = which ? sent2 : sent1;
  const float* Wih  = which ? Wih2  : Wih1;
  const float* bA   = which ? bih2  : bih1;
  const float* bB   = which ? bhh2  : bhh1;
  float*       gx   = which ? gx2   : gx1;

  float wih[D];
  #pragma unroll
  for (int k=0;k<D;k+=2){
    float2 v = *(const float2*)&Wih[j*D+k];
    wih[k]=v.x; wih[k+1]=v.y;
  }
  const float bias = bA[j] + bB[j];

  __shared__ __align__(16) float xb[8][52];
  const int row0 = chunk*96;
  for (int c=0;c<12;++c){
    const int r0 = row0 + c*8;
    #pragma unroll
    for (int q=0;q<2;++q){
      int tt = j + q*256;
      if (tt < 400){
        int r = tt/50;
        int k = tt - r*50;
        int idx = sent[r0 + r];
        xb[r][k] = emb[(size_t)idx*D + k];
      }
    }
    __syncthreads();
    for (int r=0;r<8;++r){
      float a0=bias, a1=0.f;
      #pragma unroll
      for (int k=0;k<48;k+=4){
        float4 xv = *(const float4*)&xb[r][k];
        a0 += xv.x*wih[k]   + xv.y*wih[k+1];
        a1 += xv.z*wih[k+2] + xv.w*wih[k+3];
      }
      a0 += xb[r][48]*wih[48];
      a1 += xb[r][49]*wih[49];
      gx[(size_t)(r0+r)*G4 + j] = a0+a1;
    }
    __syncthreads();
  }
}

// ---------------------------------------------------------------------------
// K1: both LSTM recurrences. 32 blocks x 512 threads: TWO batches per block
// (waves 0-3 = batch 2B, waves 4-7 = batch 2B+1). Each batch group follows
// the verified r2/r7 structure exactly (one barrier/step, per-wave hbuf
// broadcast MAC, double-buffered gates, delayed hout store, LDS-only
// barrier). The groups share barriers but have identical workloads, so no
// slack is lost; the extra waves/SIMD hide each other's LDS/trans latency.
// ---------------------------------------------------------------------------
__global__ __launch_bounds__(512, 1) void lstm_kernel(
  const float* __restrict__ gx1, const float* __restrict__ gx2,
  const float* __restrict__ Whh1, const float* __restrict__ Whh2,
  const int* __restrict__ s1_len, const int* __restrict__ s2_len,
  float* __restrict__ h1_all, float* __restrict__ out_all,
  float* __restrict__ hn_cap)
{
  const int j    = threadIdx.x;         // 0..511
  const int grp  = j >> 8;              // 0/1: which batch of the pair
  const int jL   = j & 255;             // local thread id within batch group
  const int b    = blockIdx.x*2 + grp;
  const int lane = jL & 63;
  const int wvL  = jL >> 6;             // local wave 0..3
  const int gw   = j >> 6;              // global wave 0..7
  __shared__ float gates[2][2][256];    // [grp][buf][...]
  __shared__ __align__(16) float hbuf[8][64];   // per-global-wave h copy

  float whr[64];                                // Whh row jL, natural order
  #pragma unroll
  for (int k=0;k<64;k+=4){
    float4 v = *(const float4*)&Whh1[jL*64+k];
    whr[k]=v.x; whr[k+1]=v.y; whr[k+2]=v.z; whr[k+3]=v.w;
  }

  const int is_g = (wvL==2);            // wave-uniform: gate 'g' uses tanh
  float c_reg=0.f, h_reg=0.f, gh=0.f, gc=0.f, hn=0.f;
  const int idx1 = s1_len[b*64+lane];
  const int idx2 = s2_len[b*64+lane];
  hbuf[gw][lane] = 0.f;                 // own-wave init; intra-wave ordering only

  // ---- LSTM1 ----
  {
    const float* gx = gx1 + (size_t)b*SS*G4;
    float* hout = h1_all + (size_t)b*SS*E;
    float gx_cur = gx[jL];
    float gx_n1  = gx[G4 + jL];
    float h_prev = 0.f;
    for (int s=0;s<SS;++s){
      int sn2 = (s+2<SS)? s+2 : SS-1;
      float gx_n2 = gx[(size_t)sn2*G4 + jL];
      float g0=gx_cur, g1=0.f, g2=0.f, g3=0.f;
      #pragma unroll
      for (int k=0;k<64;k+=4){
        float4 hv = *(const float4*)&hbuf[gw][k];   // broadcast read
        g0 = __builtin_fmaf(hv.x, whr[k],   g0);
        g1 = __builtin_fmaf(hv.y, whr[k+1], g1);
        g2 = __builtin_fmaf(hv.z, whr[k+2], g2);
        g3 = __builtin_fmaf(hv.w, whr[k+3], g3);
      }
      float g = (g0+g1)+(g2+g3);
      const int p = s & 1;
      gates[grp][p][jL] = is_g ? tanh_fast(g) : sigmoid_fast(g);
      barrier_lds_only();
      // redundant identical update in all 4 waves of this group
      float gi=gates[grp][p][lane], gf=gates[grp][p][64+lane];
      float gg=gates[grp][p][128+lane], go=gates[grp][p][192+lane];
      c_reg = gf*c_reg + gi*gg;
      h_reg = go * tanh_fast(c_reg);
      hbuf[gw][lane] = h_reg;
      // delayed store: write PREVIOUS step's h (never drained by barrier)
      if (wvL==0 && s>0) hout[(size_t)(s-1)*E + lane] = h_prev;
      h_prev = h_reg;
      if (s==idx1){ gh=h_reg; gc=c_reg; }
      gx_cur = gx_n1; gx_n1 = gx_n2;
      // no second barrier: next step writes the OTHER gates buffer.
    }
    if (wvL==0) hout[(size_t)(SS-1)*E + lane] = h_prev;
  }
  // ---- LSTM2 ----
  #pragma unroll
  for (int k=0;k<64;k+=4){
    float4 v = *(const float4*)&Whh2[jL*64+k];
    whr[k]=v.x; whr[k+1]=v.y; whr[k+2]=v.z; whr[k+3]=v.w;
  }
  h_reg = gh; c_reg = gc;
  hbuf[gw][lane] = gh;
  barrier_lds_only();
  {
    const float* gx = gx2 + (size_t)b*SS*G4;
    float* hout = out_all + (size_t)b*SS*E;
    float gx_cur = gx[jL];
    float gx_n1  = gx[G4 + jL];
    float h_prev = 0.f;
    for (int s=0;s<SS;++s){
      int sn2 = (s+2<SS)? s+2 : SS-1;
      float gx_n2 = gx[(size_t)sn2*G4 + jL];
      float g0=gx_cur, g1=0.f, g2=0.f, g3=0.f;
      #pragma unroll
      for (int k=0;k<64;k+=4){
        float4 hv = *(const float4*)&hbuf[gw][k];
        g0 = __builtin_fmaf(hv.x, whr[k],   g0);
        g1 = __builtin_fmaf(hv.y, whr[k+1], g1);
        g2 = __builtin_fmaf(hv.z, whr[k+2], g2);
        g3 = __builtin_fmaf(hv.w, whr[k+3], g3);
      }
      float g = (g0+g1)+(g2+g3);
      const int p = s & 1;
      gates[grp][p][jL] = is_g ? tanh_fast(g) : sigmoid_fast(g);
      barrier_lds_only();
      float gi=gates[grp][p][lane], gf=gates[grp][p][64+lane];
      float gg=gates[grp][p][128+lane], go=gates[grp][p][192+lane];
      c_reg = gf*c_reg + gi*gg;
      h_reg = go * tanh_fast(c_reg);
      hbuf[gw][lane] = h_reg;
      if (wvL==0 && s>0) hout[(size_t)(s-1)*E + lane] = h_prev;
      h_prev = h_reg;
      if (s==idx2) hn = h_reg;
      gx_cur = gx_n1; gx_n1 = gx_n2;
    }
    if (wvL==0) hout[(size_t)(SS-1)*E + lane] = h_prev;
  }
  if (wvL==0) hn_cap[b*64+lane] = hn;
}

// ---------------------------------------------------------------------------
// K2: E_g[row,f] = exp( 2*(h1[row]@wy + out[row]@wh)[f] )
// ---------------------------------------------------------------------------
__global__ __launch_bounds__(256, 1) void base_kernel(
  const float* __restrict__ h1_all, const float* __restrict__ out_all,
  const float* __restrict__ wy, const float* __restrict__ wh,
  float* __restrict__ E_g)
{
  const int t = threadIdx.x;
  const int wave = t>>6, lane = t&63;
  float wyc[E], whc[E];
  #pragma unroll
  for (int e=0;e<E;++e){ wyc[e]=wy[e*E+lane]; whc[e]=wh[e*E+lane]; }
  const int row0 = blockIdx.x*16 + wave*4;
  for (int r=0;r<4;++r){
    int row = row0 + r;
    float hv = h1_all[(size_t)row*E + lane];
    float ov = out_all[(size_t)row*E + lane];
    float a0=0,a1=0;
    #pragma unroll
    for (int e=0;e<E;++e){
      a0 += rdlane(hv,e)*wyc[e];
      a1 += rdlane(ov,e)*whc[e];
    }
    E_g[(size_t)row*E + lane] = __expf(2.0f*(a0+a1));
  }
}

// ---------------------------------------------------------------------------
// K3: attention scan. 32 blocks x 768 threads: TWO batches per block
// (threads 0-383 = batch 2B, 384-767 = batch 2B+1; 12 waves = 3/SIMD).
// Each batch group is the EXACT verified r2 structure (714 us at 6 waves).
// Groups share __syncthreads but touch disjoint LDS slices; identical
// workloads -> no slack loss. Extra waves/SIMD hide LDS/trans latency.
// ---------------------------------------------------------------------------
__global__ __launch_bounds__(768, 1) void attn_kernel(
  const float* __restrict__ h1_all, const float* __restrict__ E_all,
  const float* __restrict__ w, const float* __restrict__ wr, const float* __restrict__ wt,
  const float* __restrict__ s1_s, const int* __restrict__ s2_len,
  float* __restrict__ rn_cap)
{
  const int t   = threadIdx.x;          // 0..767
  const int grp = (t >= 384) ? 1 : 0;   // which batch of the pair
  const int tL  = t - 384*grp;          // 0..383
  const int b   = blockIdx.x*2 + grp;
  const int wv  = tL>>6, lane = tL&63;  // local wave 0..5
  const int gw  = grp*6 + wv;           // global wave slot 0..11
  const int row = wv*64 + lane;

  __shared__ float  accP[12*64];                // acc[e]-partial per wave
  __shared__ float  totP[2][8];                 // tot per wave, per group
  __shared__ float2 rwrtP[12*64];               // {rw,rt}-partial per wave
  __shared__ __align__(16) float exL[12][64];   // per-wave ex broadcast
  __shared__ __align__(16) float RlL[12][64];   // per-wave R broadcast

  const float* h1b = h1_all + (size_t)b*SS*E;
  const float* Eb  = E_all  + (size_t)b*SS*E;

  // ---- preload (once) ----
  float Ee[64];                               // E row for my s-row
  #pragma unroll
  for (int k=0;k<64;k+=4){
    float4 v = *(const float4*)&Eb[(size_t)row*E + k];
    Ee[k]=v.x; Ee[k+1]=v.y; Ee[k+2]=v.z; Ee[k+3]=v.w;
  }
  float ht[64];                               // ht[i] = h[row wv*64+i][e=lane]
  #pragma unroll
  for (int i=0;i<64;++i){
    ht[i] = h1b[(size_t)(wv*64 + i)*E + lane];
  }
  float WSUM = 0.f;
  for (int e=0;e<64;++e) WSUM += w[e];        // uniform -> scalar
  const float s1v = s1_s[b*SS + row];
  const int  idx2 = s2_len[b*E + lane];
  // GEMV k-chunk for this wave (rnew@wr, rnew@wt)
  const int k0  = (wv<4)? wv*11 : 44+(wv-4)*10;
  const int cnt = (wv<4)? 11 : 10;
  float wrch[11], wtch[11];
  #pragma unroll
  for (int jj=0;jj<11;++jj){
    int kk = k0 + ((jj<cnt)? jj : 0);
    wrch[jj] = wr[kk*E + lane];
    wtch[jj] = wt[kk*E + lane];
  }

  rwrtP[gw*64+lane] = make_float2(0.f, 0.f);   // r0 = 0 -> rw=0, rt=0
  __syncthreads();

  float rn_keep = 0.f;
  for (int s=0;s<SS;++s){
    // ---- A-pre: reduce this group's rw/rt partials (redundant per wave) ----
    float rwl=0.f, rtl=0.f;
    #pragma unroll
    for (int q=0;q<6;++q){ float2 v = rwrtP[(grp*6+q)*64+lane]; rwl+=v.x; rtl+=v.y; }
    float Rl = __expf(2.0f*rwl);      // R[e=lane], identical within group
    RlL[gw][lane] = Rl;               // intra-wave broadcast staging
    float trt = tanh_fast(rtl);       // hoisted: hides under score loop

    // ---- score: sum_e w[e]/(Ee[e]*R[e]+1), pairwise fractions, 4 chains ----
    float sc0=0.f, sc1=0.f, sc2=0.f, sc3=0.f;
    #pragma unroll
    for (int e=0;e<64;e+=8){
      float4 ra = *(const float4*)&RlL[gw][e];
      float4 rb = *(const float4*)&RlL[gw][e+4];
      float A  = __builtin_fmaf(Ee[e],  ra.x, 1.f);
      float B  = __builtin_fmaf(Ee[e+1],ra.y, 1.f);
      float C  = __builtin_fmaf(Ee[e+2],ra.z, 1.f);
      float Dv = __builtin_fmaf(Ee[e+3],ra.w, 1.f);
      float n0 = __builtin_fmaf(w[e],   B,  w[e+1]*A);
      float n1 = __builtin_fmaf(w[e+2], Dv, w[e+3]*C);
      sc0 = __builtin_fmaf(n0, fast_rcp(A*B),  sc0);
      sc1 = __builtin_fmaf(n1, fast_rcp(C*Dv), sc1);
      float A2  = __builtin_fmaf(Ee[e+4], rb.x, 1.f);
      float B2  = __builtin_fmaf(Ee[e+5], rb.y, 1.f);
      float C2  = __builtin_fmaf(Ee[e+6], rb.z, 1.f);
      float D2  = __builtin_fmaf(Ee[e+7], rb.w, 1.f);
      float n2 = __builtin_fmaf(w[e+4], B2, w[e+5]*A2);
      float n3 = __builtin_fmaf(w[e+6], D2, w[e+7]*C2);
      sc2 = __builtin_fmaf(n2, fast_rcp(A2*B2), sc2);
      sc3 = __builtin_fmaf(n3, fast_rcp(C2*D2), sc3);
    }
    float sc = WSUM - 2.0f*((sc0+sc1)+(sc2+sc3));
    float masked = s1v*sc - (1.f - s1v)*1e12f;
    float ex = __expf(masked);        // |sc| <= sum|w| ~ 51 -> fp32 safe

    // ---- MAC via intra-wave LDS broadcast: acc[e=lane] += ex[row]*h[row][e] ----
    exL[gw][lane] = ex;
    float a0=0.f, a1=0.f, a2=0.f, a3=0.f;
    #pragma unroll
    for (int i=0;i<64;i+=4){
      float4 v = *(const float4*)&exL[gw][i];   // broadcast read
      a0 = __builtin_fmaf(v.x, ht[i],   a0);
      a1 = __builtin_fmaf(v.y, ht[i+1], a1);
      a2 = __builtin_fmaf(v.z, ht[i+2], a2);
      a3 = __builtin_fmaf(v.w, ht[i+3], a3);
    }
    accP[gw*64+lane] = (a0+a1)+(a2+a3);
    float tw = wave_sum64_l63(ex);    // wave total of ex
    if (lane==63) totP[grp][wv] = tw;
    __syncthreads();

    // ---- phase C: reduce acc/tot, rnew, distributed GEMV ----
    float av=0.f;
    #pragma unroll
    for (int q=0;q<6;++q) av += accP[(grp*6+q)*64+lane];
    float tv = ((totP[grp][0]+totP[grp][1])+(totP[grp][2]+totP[grp][3]))
             + (totP[grp][4]+totP[grp][5]);
    float rnew = __builtin_fmaf(av, fast_rcp(tv), trt);
    if (wv==0 && s==idx2) rn_keep = rnew;
    float rwp=0.f, rtp=0.f;
    #pragma unroll
    for (int jj=0;jj<11;++jj){
      if (jj<cnt){
        float rv = rdlane(rnew, k0+jj);
        rwp = __builtin_fmaf(rv, wrch[jj], rwp);
        rtp = __builtin_fmaf(rv, wtch[jj], rtp);
      }
    }
    rwrtP[gw*64+lane] = make_float2(rwp, rtp);
    __syncthreads();
  }
  if (wv==0) rn_cap[b*E + lane] = rn_keep;
}

// ---------------------------------------------------------------------------
// K4: final MLP. 64 blocks x 128 threads.
// ---------------------------------------------------------------------------
__global__ __launch_bounds__(128, 1) void final_kernel(
  const float* __restrict__ rn_cap, const float* __restrict__ hn_cap,
  const float* __restrict__ wp, const float* __restrict__ wx,
  const float* __restrict__ l1W, const float* __restrict__ l1b,
  const float* __restrict__ lW, const float* __restrict__ lb,
  float* __restrict__ out)
{
  const int b = blockIdx.x, t = threadIdx.x;
  __shared__ float rn[E], hn[E], hid1[E], hid2[128];
  if (t<E){ rn[t]=rn_cap[b*E+t]; hn[t]=hn_cap[b*E+t]; }
  __syncthreads();
  if (t<E){
    float a0=0,a1=0;
    #pragma unroll
    for (int k=0;k<E;++k){
      a0 += rn[k]*wp[k*E+t];
      a1 += hn[k]*wx[k*E+t];
    }
    hid1[t] = tanh_fast(a0+a1);
  }
  __syncthreads();
  {
    float acc = l1b[t];
    #pragma unroll
    for (int k=0;k<E;++k) acc += hid1[k]*l1W[t*E+k];
    hid2[t] = tanh_fast(acc);
  }
  __syncthreads();
  if (t<4){
    float acc = lb[t];
    #pragma unroll
    for (int k=0;k<128;++k) acc += hid2[k]*lW[t*128+k];
    out[b*4+t] = acc;
  }
}

extern "C" void kernel_launch(void* const* d_in, const int* in_sizes, int n_in,
                              void* d_out, int out_size, void* d_ws, size_t ws_size,
                              hipStream_t stream)
{
  const int*   sent1 = (const int*)  d_in[0];
  const int*   sent2 = (const int*)  d_in[1];
  const int*   s1len = (const int*)  d_in[2];
  const int*   s2len = (const int*)  d_in[3];
  const float* s1s   = (const float*)d_in[4];
  const float* emb   = (const float*)d_in[6];
  const float* Wih1  = (const float*)d_in[7];
  const float* Whh1  = (const float*)d_in[8];
  const float* bih1  = (const float*)d_in[9];
  const float* bhh1  = (const float*)d_in[10];
  const float* Wih2  = (const float*)d_in[11];
  const float* Whh2  = (const float*)d_in[12];
  const float* bih2  = (const float*)d_in[13];
  const float* bhh2  = (const float*)d_in[14];
  const float* wy    = (const float*)d_in[15];
  const float* wh    = (const float*)d_in[16];
  const float* w     = (const float*)d_in[17];
  const float* wp    = (const float*)d_in[18];
  const float* wx    = (const float*)d_in[19];
  const float* wr    = (const float*)d_in[20];
  const float* wt    = (const float*)d_in[21];
  const float* l1W   = (const float*)d_in[22];
  const float* l1b   = (const float*)d_in[23];
  const float* lW    = (const float*)d_in[24];
  const float* lb    = (const float*)d_in[25];
  float* out = (float*)d_out;

  float* ws  = (float*)d_ws;
  float* gx1 = ws;                         // 64*384*256 = 6291456 floats
  float* gx2 = gx1 + 6291456;
  float* h1  = gx2 + 6291456;              // 64*384*64 = 1572864
  float* outa= h1  + 1572864;
  float* Eg  = outa + 1572864;
  float* rnc = Eg  + 1572864;              // 4096
  float* hnc = rnc + 4096;

  hipLaunchKernelGGL(gx_kernel, dim3(512), dim3(256), 0, stream,
    sent1, sent2, emb, Wih1, bih1, bhh1, Wih2, bih2, bhh2, gx1, gx2);
  hipLaunchKernelGGL(lstm_kernel, dim3(32), dim3(512), 0, stream,
    gx1, gx2, Whh1, Whh2, s1len, s2len, h1, outa, hnc);
  hipLaunchKernelGGL(base_kernel, dim3(1536), dim3(256), 0, stream,
    h1, outa, wy, wh, Eg);
  hipLaunchKernelGGL(attn_kernel, dim3(32), dim3(768), 0, stream,
    h1, Eg, w, wr, wt, s1s, s2len, rnc);
  hipLaunchKernelGGL(final_kernel, dim3(64), dim3(128), 0, stream,
    rnc, hnc, wp, wx, l1W, l1b, lW, lb, out);
}

// Round 9
// 1745.752 us; speedup vs baseline: 1.6196x; 1.6196x over previous
//
#include <hip/hip_runtime.h>

#define E 64
#define D 50
#define SS 384
#define G4 256   // 4*E

__device__ __forceinline__ float fast_rcp(float x){ return __builtin_amdgcn_rcpf(x); }
__device__ __forceinline__ float tanh_fast(float x){
  // tanh(x) = 1 - 2/(exp(2x)+1)
  float e = __expf(2.0f*x);
  return 1.0f - 2.0f*fast_rcp(e + 1.0f);
}
__device__ __forceinline__ float sigmoid_fast(float x){
  return fast_rcp(1.0f + __expf(-x));
}
__device__ __forceinline__ float rdlane(float v, int l){
  return __int_as_float(__builtin_amdgcn_readlane(__float_as_int(v), l));
}
// DPP-shifted copy with 0 for invalid source lanes (ctrl must be a literal).
#define DPP0(x, ctrl) __int_as_float(__builtin_amdgcn_update_dpp( \
    0, __float_as_int(x), ctrl, 0xF, 0xF, true))
// wave64 sum; full sum valid in lane 63 (classic row_shr + row_bcast ladder)
__device__ __forceinline__ float wave_sum64_l63(float x){
  x += DPP0(x, 0x111);  // row_shr:1
  x += DPP0(x, 0x112);  // row_shr:2
  x += DPP0(x, 0x114);  // row_shr:4
  x += DPP0(x, 0x118);  // row_shr:8
  x += DPP0(x, 0x142);  // row_bcast:15
  x += DPP0(x, 0x143);  // row_bcast:31
  return x;
}
// Block barrier that drains ONLY the LDS counter (no vmcnt(0) drain).
__device__ __forceinline__ void barrier_lds_only(){
  __builtin_amdgcn_sched_barrier(0);
  asm volatile("s_waitcnt lgkmcnt(0)" ::: "memory");
  __builtin_amdgcn_s_barrier();
  __builtin_amdgcn_sched_barrier(0);
}

// ---------------------------------------------------------------------------
// K0: gx[b,s,j] = bias[j] + sum_k emb[sent[b,s],k] * Wih[j,k]   (both LSTMs)
// ---------------------------------------------------------------------------
__global__ __launch_bounds__(256, 1) void gx_kernel(
  const int* __restrict__ sent1, const int* __restrict__ sent2,
  const float* __restrict__ emb,
  const float* __restrict__ Wih1, const float* __restrict__ bih1, const float* __restrict__ bhh1,
  const float* __restrict__ Wih2, const float* __restrict__ bih2, const float* __restrict__ bhh2,
  float* __restrict__ gx1, float* __restrict__ gx2)
{
  const int bb    = blockIdx.x;     // 0..511
  const int which = bb >> 8;
  const int chunk = bb & 255;
  const int j     = threadIdx.x;
  const int*   sent = which ? sent2 : sent1;
  const float* Wih  = which ? Wih2  : Wih1;
  const float* bA   = which ? bih2  : bih1;
  const float* bB   = which ? bhh2  : bhh1;
  float*       gx   = which ? gx2   : gx1;

  float wih[D];
  #pragma unroll
  for (int k=0;k<D;k+=2){
    float2 v = *(const float2*)&Wih[j*D+k];
    wih[k]=v.x; wih[k+1]=v.y;
  }
  const float bias = bA[j] + bB[j];

  __shared__ __align__(16) float xb[8][52];
  const int row0 = chunk*96;
  for (int c=0;c<12;++c){
    const int r0 = row0 + c*8;
    #pragma unroll
    for (int q=0;q<2;++q){
      int tt = j + q*256;
      if (tt < 400){
        int r = tt/50;
        int k = tt - r*50;
        int idx = sent[r0 + r];
        xb[r][k] = emb[(size_t)idx*D + k];
      }
    }
    __syncthreads();
    for (int r=0;r<8;++r){
      float a0=bias, a1=0.f;
      #pragma unroll
      for (int k=0;k<48;k+=4){
        float4 xv = *(const float4*)&xb[r][k];
        a0 += xv.x*wih[k]   + xv.y*wih[k+1];
        a1 += xv.z*wih[k+2] + xv.w*wih[k+3];
      }
      a0 += xb[r][48]*wih[48];
      a1 += xb[r][49]*wih[49];
      gx[(size_t)(r0+r)*G4 + j] = a0+a1;
    }
    __syncthreads();
  }
}

// ---------------------------------------------------------------------------
// K1: both LSTM recurrences. 64 blocks x 256 threads (4 waves) — r7 verified.
// One barrier/step (LDS-only), per-wave hbuf broadcast MAC, double-buffered
// gates, delayed hout store.
// ---------------------------------------------------------------------------
__global__ __launch_bounds__(256, 1) void lstm_kernel(
  const float* __restrict__ gx1, const float* __restrict__ gx2,
  const float* __restrict__ Whh1, const float* __restrict__ Whh2,
  const int* __restrict__ s1_len, const int* __restrict__ s2_len,
  float* __restrict__ h1_all, float* __restrict__ out_all,
  float* __restrict__ hn_cap)
{
  const int b = blockIdx.x;
  const int j = threadIdx.x;
  const int lane = j & 63;
  const int wv = j >> 6;
  __shared__ float gates[2][256];
  __shared__ __align__(16) float hbuf[4][64];   // per-wave private h copy

  float whr[64];                                // Whh row j, natural order
  #pragma unroll
  for (int k=0;k<64;k+=4){
    float4 v = *(const float4*)&Whh1[j*64+k];
    whr[k]=v.x; whr[k+1]=v.y; whr[k+2]=v.z; whr[k+3]=v.w;
  }

  const int is_g = (wv==2);             // wave-uniform: gate 'g' uses tanh
  float c_reg=0.f, h_reg=0.f, gh=0.f, gc=0.f, hn=0.f;
  const int idx1 = s1_len[b*64+lane];
  const int idx2 = s2_len[b*64+lane];
  hbuf[wv][lane] = 0.f;                 // own-wave init; intra-wave ordering only

  // ---- LSTM1 ----
  {
    const float* gx = gx1 + (size_t)b*SS*G4;
    float* hout = h1_all + (size_t)b*SS*E;
    float gx_cur = gx[j];
    float gx_n1  = gx[G4 + j];
    float h_prev = 0.f;
    for (int s=0;s<SS;++s){
      int sn2 = (s+2<SS)? s+2 : SS-1;
      float gx_n2 = gx[(size_t)sn2*G4 + j];
      float g0=gx_cur, g1=0.f, g2=0.f, g3=0.f;
      #pragma unroll
      for (int k=0;k<64;k+=4){
        float4 hv = *(const float4*)&hbuf[wv][k];   // broadcast read
        g0 = __builtin_fmaf(hv.x, whr[k],   g0);
        g1 = __builtin_fmaf(hv.y, whr[k+1], g1);
        g2 = __builtin_fmaf(hv.z, whr[k+2], g2);
        g3 = __builtin_fmaf(hv.w, whr[k+3], g3);
      }
      float g = (g0+g1)+(g2+g3);
      const int p = s & 1;
      gates[p][j] = is_g ? tanh_fast(g) : sigmoid_fast(g);
      barrier_lds_only();
      // redundant identical update in all 4 waves (keeps h per-wave)
      float gi=gates[p][lane], gf=gates[p][64+lane], gg=gates[p][128+lane], go=gates[p][192+lane];
      c_reg = gf*c_reg + gi*gg;
      h_reg = go * tanh_fast(c_reg);
      hbuf[wv][lane] = h_reg;
      // delayed store: write PREVIOUS step's h (never drained by barrier)
      if (wv==0 && s>0) hout[(size_t)(s-1)*E + lane] = h_prev;
      h_prev = h_reg;
      if (s==idx1){ gh=h_reg; gc=c_reg; }
      gx_cur = gx_n1; gx_n1 = gx_n2;
      // no second barrier: next step writes the OTHER gates buffer.
    }
    if (wv==0) hout[(size_t)(SS-1)*E + lane] = h_prev;
  }
  // ---- LSTM2 ----
  #pragma unroll
  for (int k=0;k<64;k+=4){
    float4 v = *(const float4*)&Whh2[j*64+k];
    whr[k]=v.x; whr[k+1]=v.y; whr[k+2]=v.z; whr[k+3]=v.w;
  }
  h_reg = gh; c_reg = gc;
  hbuf[wv][lane] = gh;
  barrier_lds_only();
  {
    const float* gx = gx2 + (size_t)b*SS*G4;
    float* hout = out_all + (size_t)b*SS*E;
    float gx_cur = gx[j];
    float gx_n1  = gx[G4 + j];
    float h_prev = 0.f;
    for (int s=0;s<SS;++s){
      int sn2 = (s+2<SS)? s+2 : SS-1;
      float gx_n2 = gx[(size_t)sn2*G4 + j];
      float g0=gx_cur, g1=0.f, g2=0.f, g3=0.f;
      #pragma unroll
      for (int k=0;k<64;k+=4){
        float4 hv = *(const float4*)&hbuf[wv][k];
        g0 = __builtin_fmaf(hv.x, whr[k],   g0);
        g1 = __builtin_fmaf(hv.y, whr[k+1], g1);
        g2 = __builtin_fmaf(hv.z, whr[k+2], g2);
        g3 = __builtin_fmaf(hv.w, whr[k+3], g3);
      }
      float g = (g0+g1)+(g2+g3);
      const int p = s & 1;
      gates[p][j] = is_g ? tanh_fast(g) : sigmoid_fast(g);
      barrier_lds_only();
      float gi=gates[p][lane], gf=gates[p][64+lane], gg=gates[p][128+lane], go=gates[p][192+lane];
      c_reg = gf*c_reg + gi*gg;
      h_reg = go * tanh_fast(c_reg);
      hbuf[wv][lane] = h_reg;
      if (wv==0 && s>0) hout[(size_t)(s-1)*E + lane] = h_prev;
      h_prev = h_reg;
      if (s==idx2) hn = h_reg;
      gx_cur = gx_n1; gx_n1 = gx_n2;
    }
    if (wv==0) hout[(size_t)(SS-1)*E + lane] = h_prev;
  }
  if (wv==0) hn_cap[b*64+lane] = hn;
}

// ---------------------------------------------------------------------------
// K2: E_g[row,f] = exp( 2*(h1[row]@wy + out[row]@wh)[f] )
// ---------------------------------------------------------------------------
__global__ __launch_bounds__(256, 1) void base_kernel(
  const float* __restrict__ h1_all, const float* __restrict__ out_all,
  const float* __restrict__ wy, const float* __restrict__ wh,
  float* __restrict__ E_g)
{
  const int t = threadIdx.x;
  const int wave = t>>6, lane = t&63;
  float wyc[E], whc[E];
  #pragma unroll
  for (int e=0;e<E;++e){ wyc[e]=wy[e*E+lane]; whc[e]=wh[e*E+lane]; }
  const int row0 = blockIdx.x*16 + wave*4;
  for (int r=0;r<4;++r){
    int row = row0 + r;
    float hv = h1_all[(size_t)row*E + lane];
    float ov = out_all[(size_t)row*E + lane];
    float a0=0,a1=0;
    #pragma unroll
    for (int e=0;e<E;++e){
      a0 += rdlane(hv,e)*wyc[e];
      a1 += rdlane(ov,e)*whc[e];
    }
    E_g[(size_t)row*E + lane] = __expf(2.0f*(a0+a1));
  }
}

// ---------------------------------------------------------------------------
// K3: attention scan. 64 blocks x 512 threads: 8 BALANCED waves, 48 rows
// each (2 waves per SIMD everywhere). Same verified r2 phase structure.
// Rationale: 6 waves sat 2,2,1,1 on the 4 SIMDs — the 2-wave SIMDs carried
// 33% of block issue each and gated every barrier; 1-wave SIMDs had zero
// latency hiding. 8x48 gives every SIMD 25% of issue + 2-way interleave.
// Per-thread regs ~153 (ht[48]+Ee[64]+2x8 chunks) < 256 budget at
// waves_per_eu(2,2) -> no spill (r8's failure mode).
// Lanes 48-63 idle only in row-owned phases; e-indexed phases use all 64.
// ---------------------------------------------------------------------------
#define RPW 48   // rows per wave
__global__ __attribute__((amdgpu_flat_work_group_size(512,512), amdgpu_waves_per_eu(2,2)))
void attn_kernel(
  const float* __restrict__ h1_all, const float* __restrict__ E_all,
  const float* __restrict__ w, const float* __restrict__ wr, const float* __restrict__ wt,
  const float* __restrict__ s1_s, const int* __restrict__ s2_len,
  float* __restrict__ rn_cap)
{
  const int b = blockIdx.x;
  const int t = threadIdx.x;            // 0..511
  const int wv = t>>6, lane = t&63;     // 8 waves
  const bool owner = (lane < RPW);
  const int row = wv*RPW + (owner ? lane : RPW-1);   // clamped for safe loads

  __shared__ float  accP[8*64];                 // acc[e]-partial per wave
  __shared__ float  totP[8];                    // tot per wave
  __shared__ float2 rwrtP[8*64];                // {rw,rt}-partial per wave
  __shared__ __align__(16) float exL[8][RPW];   // per-wave ex broadcast (owners)
  __shared__ __align__(16) float RlL[8][64];    // per-wave R broadcast

  const float* h1b = h1_all + (size_t)b*SS*E;
  const float* Eb  = E_all  + (size_t)b*SS*E;

  // ---- preload (once) ----
  float Ee[64];                               // E row for my s-row (dup if !owner)
  #pragma unroll
  for (int k=0;k<64;k+=4){
    float4 v = *(const float4*)&Eb[(size_t)row*E + k];
    Ee[k]=v.x; Ee[k+1]=v.y; Ee[k+2]=v.z; Ee[k+3]=v.w;
  }
  float ht[RPW];                              // ht[i] = h[wv*RPW+i][e=lane], all lanes
  #pragma unroll
  for (int i=0;i<RPW;++i){
    ht[i] = h1b[(size_t)(wv*RPW + i)*E + lane];
  }
  float WSUM = 0.f;
  for (int e=0;e<64;++e) WSUM += w[e];        // uniform -> scalar
  const float s1v = s1_s[b*SS + row];
  const int  idx2 = s2_len[b*E + lane];
  // GEMV k-chunk for this wave (rnew@wr, rnew@wt): 8 k's per wave
  const int k0 = wv*8;
  float wrch[8], wtch[8];
  #pragma unroll
  for (int jj=0;jj<8;++jj){
    wrch[jj] = wr[(k0+jj)*E + lane];
    wtch[jj] = wt[(k0+jj)*E + lane];
  }

  rwrtP[t&511] = make_float2(0.f, 0.f);   // t in [0,512): covers all 8*64
  __syncthreads();

  float rn_keep = 0.f;
  for (int s=0;s<SS;++s){
    // ---- A-pre: reduce rw/rt partials (redundant per wave, 8 b64 reads) ----
    float rwl=0.f, rtl=0.f;
    #pragma unroll
    for (int q=0;q<8;++q){ float2 v = rwrtP[q*64+lane]; rwl+=v.x; rtl+=v.y; }
    float Rl = __expf(2.0f*rwl);      // R[e=lane], identical in every wave
    RlL[wv][lane] = Rl;               // intra-wave broadcast staging
    float trt = tanh_fast(rtl);       // hoisted: hides under score loop

    // ---- score: sum_e w[e]/(Ee[e]*R[e]+1), pairwise fractions, 4 chains ----
    float sc0=0.f, sc1=0.f, sc2=0.f, sc3=0.f;
    #pragma unroll
    for (int e=0;e<64;e+=8){
      float4 ra = *(const float4*)&RlL[wv][e];
      float4 rb = *(const float4*)&RlL[wv][e+4];
      float A  = __builtin_fmaf(Ee[e],  ra.x, 1.f);
      float B  = __builtin_fmaf(Ee[e+1],ra.y, 1.f);
      float C  = __builtin_fmaf(Ee[e+2],ra.z, 1.f);
      float Dv = __builtin_fmaf(Ee[e+3],ra.w, 1.f);
      float n0 = __builtin_fmaf(w[e],   B,  w[e+1]*A);
      float n1 = __builtin_fmaf(w[e+2], Dv, w[e+3]*C);
      sc0 = __builtin_fmaf(n0, fast_rcp(A*B),  sc0);
      sc1 = __builtin_fmaf(n1, fast_rcp(C*Dv), sc1);
      float A2  = __builtin_fmaf(Ee[e+4], rb.x, 1.f);
      float B2  = __builtin_fmaf(Ee[e+5], rb.y, 1.f);
      float C2  = __builtin_fmaf(Ee[e+6], rb.z, 1.f);
      float D2  = __builtin_fmaf(Ee[e+7], rb.w, 1.f);
      float n2 = __builtin_fmaf(w[e+4], B2, w[e+5]*A2);
      float n3 = __builtin_fmaf(w[e+6], D2, w[e+7]*C2);
      sc2 = __builtin_fmaf(n2, fast_rcp(A2*B2), sc2);
      sc3 = __builtin_fmaf(n3, fast_rcp(C2*D2), sc3);
    }
    float sc = WSUM - 2.0f*((sc0+sc1)+(sc2+sc3));
    float masked = s1v*sc - (1.f - s1v)*1e12f;
    float ex = __expf(masked);        // |sc| <= sum|w| ~ 51 -> fp32 safe

    // ---- MAC via intra-wave LDS broadcast over this wave's 48 rows ----
    if (owner) exL[wv][lane] = ex;
    float a0=0.f, a1=0.f, a2=0.f, a3=0.f;
    #pragma unroll
    for (int i=0;i<RPW;i+=4){
      float4 v = *(const float4*)&exL[wv][i];   // broadcast read
      a0 = __builtin_fmaf(v.x, ht[i],   a0);
      a1 = __builtin_fmaf(v.y, ht[i+1], a1);
      a2 = __builtin_fmaf(v.z, ht[i+2], a2);
      a3 = __builtin_fmaf(v.w, ht[i+3], a3);
    }
    accP[wv*64+lane] = (a0+a1)+(a2+a3);
    float exm = owner ? ex : 0.f;
    float tw = wave_sum64_l63(exm);   // wave total of ex over its 48 rows
    if (lane==63) totP[wv] = tw;
    __syncthreads();

    // ---- phase C: reduce acc/tot, rnew, distributed GEMV ----
    float av=0.f;
    #pragma unroll
    for (int q=0;q<8;++q) av += accP[q*64+lane];
    float tv = ((totP[0]+totP[1])+(totP[2]+totP[3]))
             + ((totP[4]+totP[5])+(totP[6]+totP[7]));
    float rnew = __builtin_fmaf(av, fast_rcp(tv), trt);
    if (wv==0 && s==idx2) rn_keep = rnew;
    float rwp=0.f, rtp=0.f;
    #pragma unroll
    for (int jj=0;jj<8;++jj){
      float rv = rdlane(rnew, k0+jj);
      rwp = __builtin_fmaf(rv, wrch[jj], rwp);
      rtp = __builtin_fmaf(rv, wtch[jj], rtp);
    }
    rwrtP[wv*64+lane] = make_float2(rwp, rtp);
    __syncthreads();
  }
  if (wv==0) rn_cap[b*E + lane] = rn_keep;
}

// ---------------------------------------------------------------------------
// K4: final MLP. 64 blocks x 128 threads.
// ---------------------------------------------------------------------------
__global__ __launch_bounds__(128, 1) void final_kernel(
  const float* __restrict__ rn_cap, const float* __restrict__ hn_cap,
  const float* __restrict__ wp, const float* __restrict__ wx,
  const float* __restrict__ l1W, const float* __restrict__ l1b,
  const float* __restrict__ lW, const float* __restrict__ lb,
  float* __restrict__ out)
{
  const int b = blockIdx.x, t = threadIdx.x;
  __shared__ float rn[E], hn[E], hid1[E], hid2[128];
  if (t<E){ rn[t]=rn_cap[b*E+t]; hn[t]=hn_cap[b*E+t]; }
  __syncthreads();
  if (t<E){
    float a0=0,a1=0;
    #pragma unroll
    for (int k=0;k<E;++k){
      a0 += rn[k]*wp[k*E+t];
      a1 += hn[k]*wx[k*E+t];
    }
    hid1[t] = tanh_fast(a0+a1);
  }
  __syncthreads();
  {
    float acc = l1b[t];
    #pragma unroll
    for (int k=0;k<E;++k) acc += hid1[k]*l1W[t*E+k];
    hid2[t] = tanh_fast(acc);
  }
  __syncthreads();
  if (t<4){
    float acc = lb[t];
    #pragma unroll
    for (int k=0;k<128;++k) acc += hid2[k]*lW[t*128+k];
    out[b*4+t] = acc;
  }
}

extern "C" void kernel_launch(void* const* d_in, const int* in_sizes, int n_in,
                              void* d_out, int out_size, void* d_ws, size_t ws_size,
                              hipStream_t stream)
{
  const int*   sent1 = (const int*)  d_in[0];
  const int*   sent2 = (const int*)  d_in[1];
  const int*   s1len = (const int*)  d_in[2];
  const int*   s2len = (const int*)  d_in[3];
  const float* s1s   = (const float*)d_in[4];
  const float* emb   = (const float*)d_in[6];
  const float* Wih1  = (const float*)d_in[7];
  const float* Whh1  = (const float*)d_in[8];
  const float* bih1  = (const float*)d_in[9];
  const float* bhh1  = (const float*)d_in[10];
  const float* Wih2  = (const float*)d_in[11];
  const float* Whh2  = (const float*)d_in[12];
  const float* bih2  = (const float*)d_in[13];
  const float* bhh2  = (const float*)d_in[14];
  const float* wy    = (const float*)d_in[15];
  const float* wh    = (const float*)d_in[16];
  const float* w     = (const float*)d_in[17];
  const float* wp    = (const float*)d_in[18];
  const float* wx    = (const float*)d_in[19];
  const float* wr    = (const float*)d_in[20];
  const float* wt    = (const float*)d_in[21];
  const float* l1W   = (const float*)d_in[22];
  const float* l1b   = (const float*)d_in[23];
  const float* lW    = (const float*)d_in[24];
  const float* lb    = (const float*)d_in[25];
  float* out = (float*)d_out;

  float* ws  = (float*)d_ws;
  float* gx1 = ws;                         // 64*384*256 = 6291456 floats
  float* gx2 = gx1 + 6291456;
  float* h1  = gx2 + 6291456;              // 64*384*64 = 1572864
  float* outa= h1  + 1572864;
  float* Eg  = outa + 1572864;
  float* rnc = Eg  + 1572864;              // 4096
  float* hnc = rnc + 4096;

  hipLaunchKernelGGL(gx_kernel, dim3(512), dim3(256), 0, stream,
    sent1, sent2, emb, Wih1, bih1, bhh1, Wih2, bih2, bhh2, gx1, gx2);
  hipLaunchKernelGGL(lstm_kernel, dim3(64), dim3(256), 0, stream,
    gx1, gx2, Whh1, Whh2, s1len, s2len, h1, outa, hnc);
  hipLaunchKernelGGL(base_kernel, dim3(1536), dim3(256), 0, stream,
    h1, outa, wy, wh, Eg);
  hipLaunchKernelGGL(attn_kernel, dim3(64), dim3(512), 0, stream,
    h1, Eg, w, wr, wt, s1s, s2len, rnc);
  hipLaunchKernelGGL(final_kernel, dim3(64), dim3(128), 0, stream,
    rnc, hnc, wp, wx, l1W, l1b, lW, lb, out);
}

// Round 10
// 1409.459 us; speedup vs baseline: 2.0060x; 1.2386x over previous
//
#include <hip/hip_runtime.h>

#define E 64
#define D 50
#define SS 384
#define G4 256   // 4*E

__device__ __forceinline__ float fast_rcp(float x){ return __builtin_amdgcn_rcpf(x); }
__device__ __forceinline__ float tanh_fast(float x){
  // tanh(x) = 1 - 2/(exp(2x)+1)
  float e = __expf(2.0f*x);
  return 1.0f - 2.0f*fast_rcp(e + 1.0f);
}
__device__ __forceinline__ float sigmoid_fast(float x){
  return fast_rcp(1.0f + __expf(-x));
}
__device__ __forceinline__ float rdlane(float v, int l){
  return __int_as_float(__builtin_amdgcn_readlane(__float_as_int(v), l));
}
// whole-wave rotate via DPP (VALU pipe, NOT the DS pipe).
// wave_ror:1: lane i receives the value of lane (i-1)&63.
__device__ __forceinline__ float ror1(float x){
  return __int_as_float(__builtin_amdgcn_update_dpp(
      0, __float_as_int(x), 0x13C /*wave_ror:1*/, 0xF, 0xF, false));
}
// DPP-shifted copy with 0 for invalid source lanes (ctrl must be a literal).
#define DPP0(x, ctrl) __int_as_float(__builtin_amdgcn_update_dpp( \
    0, __float_as_int(x), ctrl, 0xF, 0xF, true))
// wave64 sum; full sum valid in lane 63 (classic row_shr + row_bcast ladder)
__device__ __forceinline__ float wave_sum64_l63(float x){
  x += DPP0(x, 0x111);  // row_shr:1
  x += DPP0(x, 0x112);  // row_shr:2
  x += DPP0(x, 0x114);  // row_shr:4
  x += DPP0(x, 0x118);  // row_shr:8
  x += DPP0(x, 0x142);  // row_bcast:15
  x += DPP0(x, 0x143);  // row_bcast:31
  return x;
}
// Block barrier that drains ONLY the LDS counter (no vmcnt(0) drain).
__device__ __forceinline__ void barrier_lds_only(){
  __builtin_amdgcn_sched_barrier(0);
  asm volatile("s_waitcnt lgkmcnt(0)" ::: "memory");
  __builtin_amdgcn_s_barrier();
  __builtin_amdgcn_sched_barrier(0);
}

// ---------------------------------------------------------------------------
// K0: gx[b,s,j] = bias[j] + sum_k emb[sent[b,s],k] * Wih[j,k]   (both LSTMs)
// ---------------------------------------------------------------------------
__global__ __launch_bounds__(256, 1) void gx_kernel(
  const int* __restrict__ sent1, const int* __restrict__ sent2,
  const float* __restrict__ emb,
  const float* __restrict__ Wih1, const float* __restrict__ bih1, const float* __restrict__ bhh1,
  const float* __restrict__ Wih2, const float* __restrict__ bih2, const float* __restrict__ bhh2,
  float* __restrict__ gx1, float* __restrict__ gx2)
{
  const int bb    = blockIdx.x;     // 0..511
  const int which = bb >> 8;
  const int chunk = bb & 255;
  const int j     = threadIdx.x;
  const int*   sent = which ? sent2 : sent1;
  const float* Wih  = which ? Wih2  : Wih1;
  const float* bA   = which ? bih2  : bih1;
  const float* bB   = which ? bhh2  : bhh1;
  float*       gx   = which ? gx2   : gx1;

  float wih[D];
  #pragma unroll
  for (int k=0;k<D;k+=2){
    float2 v = *(const float2*)&Wih[j*D+k];
    wih[k]=v.x; wih[k+1]=v.y;
  }
  const float bias = bA[j] + bB[j];

  __shared__ __align__(16) float xb[8][52];
  const int row0 = chunk*96;
  for (int c=0;c<12;++c){
    const int r0 = row0 + c*8;
    #pragma unroll
    for (int q=0;q<2;++q){
      int tt = j + q*256;
      if (tt < 400){
        int r = tt/50;
        int k = tt - r*50;
        int idx = sent[r0 + r];
        xb[r][k] = emb[(size_t)idx*D + k];
      }
    }
    __syncthreads();
    for (int r=0;r<8;++r){
      float a0=bias, a1=0.f;
      #pragma unroll
      for (int k=0;k<48;k+=4){
        float4 xv = *(const float4*)&xb[r][k];
        a0 += xv.x*wih[k]   + xv.y*wih[k+1];
        a1 += xv.z*wih[k+2] + xv.w*wih[k+3];
      }
      a0 += xb[r][48]*wih[48];
      a1 += xb[r][49]*wih[49];
      gx[(size_t)(r0+r)*G4 + j] = a0+a1;
    }
    __syncthreads();
  }
}

// ---------------------------------------------------------------------------
// K1: both LSTM recurrences. 64 blocks x 256 threads (4 waves) — r7 verified.
// One barrier/step (LDS-only), per-wave hbuf broadcast MAC, double-buffered
// gates, delayed hout store.
// ---------------------------------------------------------------------------
__global__ __launch_bounds__(256, 1) void lstm_kernel(
  const float* __restrict__ gx1, const float* __restrict__ gx2,
  const float* __restrict__ Whh1, const float* __restrict__ Whh2,
  const int* __restrict__ s1_len, const int* __restrict__ s2_len,
  float* __restrict__ h1_all, float* __restrict__ out_all,
  float* __restrict__ hn_cap)
{
  const int b = blockIdx.x;
  const int j = threadIdx.x;
  const int lane = j & 63;
  const int wv = j >> 6;
  __shared__ float gates[2][256];
  __shared__ __align__(16) float hbuf[4][64];   // per-wave private h copy

  float whr[64];                                // Whh row j, natural order
  #pragma unroll
  for (int k=0;k<64;k+=4){
    float4 v = *(const float4*)&Whh1[j*64+k];
    whr[k]=v.x; whr[k+1]=v.y; whr[k+2]=v.z; whr[k+3]=v.w;
  }

  const int is_g = (wv==2);             // wave-uniform: gate 'g' uses tanh
  float c_reg=0.f, h_reg=0.f, gh=0.f, gc=0.f, hn=0.f;
  const int idx1 = s1_len[b*64+lane];
  const int idx2 = s2_len[b*64+lane];
  hbuf[wv][lane] = 0.f;                 // own-wave init; intra-wave ordering only

  // ---- LSTM1 ----
  {
    const float* gx = gx1 + (size_t)b*SS*G4;
    float* hout = h1_all + (size_t)b*SS*E;
    float gx_cur = gx[j];
    float gx_n1  = gx[G4 + j];
    float h_prev = 0.f;
    for (int s=0;s<SS;++s){
      int sn2 = (s+2<SS)? s+2 : SS-1;
      float gx_n2 = gx[(size_t)sn2*G4 + j];
      float g0=gx_cur, g1=0.f, g2=0.f, g3=0.f;
      #pragma unroll
      for (int k=0;k<64;k+=4){
        float4 hv = *(const float4*)&hbuf[wv][k];   // broadcast read
        g0 = __builtin_fmaf(hv.x, whr[k],   g0);
        g1 = __builtin_fmaf(hv.y, whr[k+1], g1);
        g2 = __builtin_fmaf(hv.z, whr[k+2], g2);
        g3 = __builtin_fmaf(hv.w, whr[k+3], g3);
      }
      float g = (g0+g1)+(g2+g3);
      const int p = s & 1;
      gates[p][j] = is_g ? tanh_fast(g) : sigmoid_fast(g);
      barrier_lds_only();
      // redundant identical update in all 4 waves (keeps h per-wave)
      float gi=gates[p][lane], gf=gates[p][64+lane], gg=gates[p][128+lane], go=gates[p][192+lane];
      c_reg = gf*c_reg + gi*gg;
      h_reg = go * tanh_fast(c_reg);
      hbuf[wv][lane] = h_reg;
      // delayed store: write PREVIOUS step's h (never drained by barrier)
      if (wv==0 && s>0) hout[(size_t)(s-1)*E + lane] = h_prev;
      h_prev = h_reg;
      if (s==idx1){ gh=h_reg; gc=c_reg; }
      gx_cur = gx_n1; gx_n1 = gx_n2;
      // no second barrier: next step writes the OTHER gates buffer.
    }
    if (wv==0) hout[(size_t)(SS-1)*E + lane] = h_prev;
  }
  // ---- LSTM2 ----
  #pragma unroll
  for (int k=0;k<64;k+=4){
    float4 v = *(const float4*)&Whh2[j*64+k];
    whr[k]=v.x; whr[k+1]=v.y; whr[k+2]=v.z; whr[k+3]=v.w;
  }
  h_reg = gh; c_reg = gc;
  hbuf[wv][lane] = gh;
  barrier_lds_only();
  {
    const float* gx = gx2 + (size_t)b*SS*G4;
    float* hout = out_all + (size_t)b*SS*E;
    float gx_cur = gx[j];
    float gx_n1  = gx[G4 + j];
    float h_prev = 0.f;
    for (int s=0;s<SS;++s){
      int sn2 = (s+2<SS)? s+2 : SS-1;
      float gx_n2 = gx[(size_t)sn2*G4 + j];
      float g0=gx_cur, g1=0.f, g2=0.f, g3=0.f;
      #pragma unroll
      for (int k=0;k<64;k+=4){
        float4 hv = *(const float4*)&hbuf[wv][k];
        g0 = __builtin_fmaf(hv.x, whr[k],   g0);
        g1 = __builtin_fmaf(hv.y, whr[k+1], g1);
        g2 = __builtin_fmaf(hv.z, whr[k+2], g2);
        g3 = __builtin_fmaf(hv.w, whr[k+3], g3);
      }
      float g = (g0+g1)+(g2+g3);
      const int p = s & 1;
      gates[p][j] = is_g ? tanh_fast(g) : sigmoid_fast(g);
      barrier_lds_only();
      float gi=gates[p][lane], gf=gates[p][64+lane], gg=gates[p][128+lane], go=gates[p][192+lane];
      c_reg = gf*c_reg + gi*gg;
      h_reg = go * tanh_fast(c_reg);
      hbuf[wv][lane] = h_reg;
      if (wv==0 && s>0) hout[(size_t)(s-1)*E + lane] = h_prev;
      h_prev = h_reg;
      if (s==idx2) hn = h_reg;
      gx_cur = gx_n1; gx_n1 = gx_n2;
    }
    if (wv==0) hout[(size_t)(SS-1)*E + lane] = h_prev;
  }
  if (wv==0) hn_cap[b*64+lane] = hn;
}

// ---------------------------------------------------------------------------
// K2: E_g[row,f] = exp( 2*(h1[row]@wy + out[row]@wh)[f] )
// ---------------------------------------------------------------------------
__global__ __launch_bounds__(256, 1) void base_kernel(
  const float* __restrict__ h1_all, const float* __restrict__ out_all,
  const float* __restrict__ wy, const float* __restrict__ wh,
  float* __restrict__ E_g)
{
  const int t = threadIdx.x;
  const int wave = t>>6, lane = t&63;
  float wyc[E], whc[E];
  #pragma unroll
  for (int e=0;e<E;++e){ wyc[e]=wy[e*E+lane]; whc[e]=wh[e*E+lane]; }
  const int row0 = blockIdx.x*16 + wave*4;
  for (int r=0;r<4;++r){
    int row = row0 + r;
    float hv = h1_all[(size_t)row*E + lane];
    float ov = out_all[(size_t)row*E + lane];
    float a0=0,a1=0;
    #pragma unroll
    for (int e=0;e<E;++e){
      a0 += rdlane(hv,e)*wyc[e];
      a1 += rdlane(ov,e)*whc[e];
    }
    E_g[(size_t)row*E + lane] = __expf(2.0f*(a0+a1));
  }
}

// ---------------------------------------------------------------------------
// K3: attention scan. 64 blocks x 384 threads (6 waves), 384 steps.
// r2 verified structure (714 us) with DS-pipe relief (theory: ~360 DS-instr
// per block-step on the single DS pipe ≈ the measured 4460 cyc/step):
//  - MAC via DPP rotate (r1-verified code + rotated ht layout): deletes the
//    exL write + 16 b128 reads per wave-step; runs on VALU pipe instead.
//  - tot packed into accP float2 (r6-verified packing): deletes totP write
//    + 6 b32 reads.
// DS ops per wave-step: ~60 -> ~32. Score loop/barriers/phase order exact.
// ---------------------------------------------------------------------------
__global__ __launch_bounds__(384, 1) void attn_kernel(
  const float* __restrict__ h1_all, const float* __restrict__ E_all,
  const float* __restrict__ w, const float* __restrict__ wr, const float* __restrict__ wt,
  const float* __restrict__ s1_s, const int* __restrict__ s2_len,
  float* __restrict__ rn_cap)
{
  const int b = blockIdx.x;
  const int t = threadIdx.x;
  const int wv = t>>6, lane = t&63;
  const int row = wv*64 + lane;

  __shared__ float2 accP2[6*64];                // {acc[e]-partial, wave tot}
  __shared__ float2 rwrtP[6*64];                // {rw,rt}-partial per wave
  __shared__ __align__(16) float RlL[6][64];    // per-wave R broadcast

  const float* h1b = h1_all + (size_t)b*SS*E;
  const float* Eb  = E_all  + (size_t)b*SS*E;

  // ---- preload (once) ----
  float Ee[64];                               // E row for my s-row
  #pragma unroll
  for (int k=0;k<64;k+=4){
    float4 v = *(const float4*)&Eb[(size_t)row*E + k];
    Ee[k]=v.x; Ee[k+1]=v.y; Ee[k+2]=v.z; Ee[k+3]=v.w;
  }
  float ht[64];   // ROTATED layout (r1-verified): ht[i] = h[(lane-i)&63 row of wave][lane]
  #pragma unroll
  for (int i=0;i<32;++i){
    ht[i]    = h1b[(size_t)(wv*64 + ((lane-i)&63))*E + lane];
    ht[i+32] = h1b[(size_t)(wv*64 + ((lane-i+32)&63))*E + lane];
  }
  float WSUM = 0.f;
  for (int e=0;e<64;++e) WSUM += w[e];        // uniform -> scalar
  const float s1v = s1_s[b*SS + row];
  const int  idx2 = s2_len[b*E + lane];
  // GEMV k-chunk for this wave (rnew@wr, rnew@wt)
  const int k0  = (wv<4)? wv*11 : 44+(wv-4)*10;
  const int cnt = (wv<4)? 11 : 10;
  float wrch[11], wtch[11];
  #pragma unroll
  for (int jj=0;jj<11;++jj){
    int kk = k0 + ((jj<cnt)? jj : 0);
    wrch[jj] = wr[kk*E + lane];
    wtch[jj] = wt[kk*E + lane];
  }

  rwrtP[t] = make_float2(0.f, 0.f);   // r0 = 0 -> rw=0, rt=0
  __syncthreads();

  float rn_keep = 0.f;
  for (int s=0;s<SS;++s){
    // ---- A-pre: reduce rw/rt partials (redundant per wave, 6 b64 reads) ----
    float rwl=0.f, rtl=0.f;
    #pragma unroll
    for (int q=0;q<6;++q){ float2 v = rwrtP[q*64+lane]; rwl+=v.x; rtl+=v.y; }
    float Rl = __expf(2.0f*rwl);      // R[e=lane], identical in every wave
    RlL[wv][lane] = Rl;               // intra-wave broadcast staging

    // ---- score: sum_e w[e]/(Ee[e]*R[e]+1), pairwise fractions, 4 chains ----
    float sc0=0.f, sc1=0.f, sc2=0.f, sc3=0.f;
    #pragma unroll
    for (int e=0;e<64;e+=8){
      float4 ra = *(const float4*)&RlL[wv][e];
      float4 rb = *(const float4*)&RlL[wv][e+4];
      float A  = __builtin_fmaf(Ee[e],  ra.x, 1.f);
      float B  = __builtin_fmaf(Ee[e+1],ra.y, 1.f);
      float C  = __builtin_fmaf(Ee[e+2],ra.z, 1.f);
      float Dv = __builtin_fmaf(Ee[e+3],ra.w, 1.f);
      float n0 = __builtin_fmaf(w[e],   B,  w[e+1]*A);
      float n1 = __builtin_fmaf(w[e+2], Dv, w[e+3]*C);
      sc0 = __builtin_fmaf(n0, fast_rcp(A*B),  sc0);
      sc1 = __builtin_fmaf(n1, fast_rcp(C*Dv), sc1);
      float A2  = __builtin_fmaf(Ee[e+4], rb.x, 1.f);
      float B2  = __builtin_fmaf(Ee[e+5], rb.y, 1.f);
      float C2  = __builtin_fmaf(Ee[e+6], rb.z, 1.f);
      float D2  = __builtin_fmaf(Ee[e+7], rb.w, 1.f);
      float n2 = __builtin_fmaf(w[e+4], B2, w[e+5]*A2);
      float n3 = __builtin_fmaf(w[e+6], D2, w[e+7]*C2);
      sc2 = __builtin_fmaf(n2, fast_rcp(A2*B2), sc2);
      sc3 = __builtin_fmaf(n3, fast_rcp(C2*D2), sc3);
    }
    float sc = WSUM - 2.0f*((sc0+sc1)+(sc2+sc3));
    float masked = s1v*sc - (1.f - s1v)*1e12f;
    float ex = __expf(masked);        // |sc| <= sum|w| ~ 51 -> fp32 safe

    // ---- MAC via DPP rotate (VALU pipe, no LDS): two independent chains ----
    float exr  = ex;                  // iter i: ex[row (lane-i)&63]
    float exr2 = __shfl_xor(ex, 32);  // iter i: ex[row (lane-i+32)&63]
    float ma=0.f, mb=0.f;
    #pragma unroll
    for (int i=0;i<32;++i){
      ma = __builtin_fmaf(exr,  ht[i],    ma);
      mb = __builtin_fmaf(exr2, ht[i+32], mb);
      exr = ror1(exr); exr2 = ror1(exr2);
    }
    float tw = rdlane(wave_sum64_l63(ex), 63);  // wave total, all lanes
    accP2[wv*64+lane] = make_float2(ma+mb, tw);
    __syncthreads();

    // ---- phase C: reduce acc/tot, rnew, distributed GEMV ----
    float av=0.f, tv=0.f;
    #pragma unroll
    for (int q=0;q<6;++q){ float2 v = accP2[q*64+lane]; av+=v.x; tv+=v.y; }
    float rnew = __builtin_fmaf(av, fast_rcp(tv), tanh_fast(rtl));
    if (wv==0 && s==idx2) rn_keep = rnew;
    float rwp=0.f, rtp=0.f;
    #pragma unroll
    for (int jj=0;jj<11;++jj){
      if (jj<cnt){
        float rv = rdlane(rnew, k0+jj);
        rwp = __builtin_fmaf(rv, wrch[jj], rwp);
        rtp = __builtin_fmaf(rv, wtch[jj], rtp);
      }
    }
    rwrtP[wv*64+lane] = make_float2(rwp, rtp);
    __syncthreads();
  }
  if (wv==0) rn_cap[b*E + lane] = rn_keep;
}

// ---------------------------------------------------------------------------
// K4: final MLP. 64 blocks x 128 threads.
// ---------------------------------------------------------------------------
__global__ __launch_bounds__(128, 1) void final_kernel(
  const float* __restrict__ rn_cap, const float* __restrict__ hn_cap,
  const float* __restrict__ wp, const float* __restrict__ wx,
  const float* __restrict__ l1W, const float* __restrict__ l1b,
  const float* __restrict__ lW, const float* __restrict__ lb,
  float* __restrict__ out)
{
  const int b = blockIdx.x, t = threadIdx.x;
  __shared__ float rn[E], hn[E], hid1[E], hid2[128];
  if (t<E){ rn[t]=rn_cap[b*E+t]; hn[t]=hn_cap[b*E+t]; }
  __syncthreads();
  if (t<E){
    float a0=0,a1=0;
    #pragma unroll
    for (int k=0;k<E;++k){
      a0 += rn[k]*wp[k*E+t];
      a1 += hn[k]*wx[k*E+t];
    }
    hid1[t] = tanh_fast(a0+a1);
  }
  __syncthreads();
  {
    float acc = l1b[t];
    #pragma unroll
    for (int k=0;k<E;++k) acc += hid1[k]*l1W[t*E+k];
    hid2[t] = tanh_fast(acc);
  }
  __syncthreads();
  if (t<4){
    float acc = lb[t];
    #pragma unroll
    for (int k=0;k<128;++k) acc += hid2[k]*lW[t*128+k];
    out[b*4+t] = acc;
  }
}

extern "C" void kernel_launch(void* const* d_in, const int* in_sizes, int n_in,
                              void* d_out, int out_size, void* d_ws, size_t ws_size,
                              hipStream_t stream)
{
  const int*   sent1 = (const int*)  d_in[0];
  const int*   sent2 = (const int*)  d_in[1];
  const int*   s1len = (const int*)  d_in[2];
  const int*   s2len = (const int*)  d_in[3];
  const float* s1s   = (const float*)d_in[4];
  const float* emb   = (const float*)d_in[6];
  const float* Wih1  = (const float*)d_in[7];
  const float* Whh1  = (const float*)d_in[8];
  const float* bih1  = (const float*)d_in[9];
  const float* bhh1  = (const float*)d_in[10];
  const float* Wih2  = (const float*)d_in[11];
  const float* Whh2  = (const float*)d_in[12];
  const float* bih2  = (const float*)d_in[13];
  const float* bhh2  = (const float*)d_in[14];
  const float* wy    = (const float*)d_in[15];
  const float* wh    = (const float*)d_in[16];
  const float* w     = (const float*)d_in[17];
  const float* wp    = (const float*)d_in[18];
  const float* wx    = (const float*)d_in[19];
  const float* wr    = (const float*)d_in[20];
  const float* wt    = (const float*)d_in[21];
  const float* l1W   = (const float*)d_in[22];
  const float* l1b   = (const float*)d_in[23];
  const float* lW    = (const float*)d_in[24];
  const float* lb    = (const float*)d_in[25];
  float* out = (float*)d_out;

  float* ws  = (float*)d_ws;
  float* gx1 = ws;                         // 64*384*256 = 6291456 floats
  float* gx2 = gx1 + 6291456;
  float* h1  = gx2 + 6291456;              // 64*384*64 = 1572864
  float* outa= h1  + 1572864;
  float* Eg  = outa + 1572864;
  float* rnc = Eg  + 1572864;              // 4096
  float* hnc = rnc + 4096;

  hipLaunchKernelGGL(gx_kernel, dim3(512), dim3(256), 0, stream,
    sent1, sent2, emb, Wih1, bih1, bhh1, Wih2, bih2, bhh2, gx1, gx2);
  hipLaunchKernelGGL(lstm_kernel, dim3(64), dim3(256), 0, stream,
    gx1, gx2, Whh1, Whh2, s1len, s2len, h1, outa, hnc);
  hipLaunchKernelGGL(base_kernel, dim3(1536), dim3(256), 0, stream,
    h1, outa, wy, wh, Eg);
  hipLaunchKernelGGL(attn_kernel, dim3(64), dim3(384), 0, stream,
    h1, Eg, w, wr, wt, s1s, s2len, rnc);
  hipLaunchKernelGGL(final_kernel, dim3(64), dim3(128), 0, stream,
    rnc, hnc, wp, wx, l1W, l1b, lW, lb, out);
}